// Round 5
// baseline (4191.501 us; speedup 1.0000x reference)
//
#include <hip/hip_runtime.h>
#include <math.h>

#define JJ 2048
#define II 16
#define NN 64
#define DD 32
#define BBATCH 32

#define JC 16        // j's per block
#define THREADS 512  // 8 waves: (bq 0..3) x (dh 0..1), lane = n
#define BSUB 16      // batches per block (half of 32)

typedef unsigned int u32;

__device__ __forceinline__ void gload_lds16(const void* g, void* l) {
    __builtin_amdgcn_global_load_lds(
        (const __attribute__((address_space(1))) u32*)g,
        (__attribute__((address_space(3))) u32*)l, 16, 0, 0);
}

__device__ __forceinline__ float dot4(const float4 a, const float4 b) {
    return fmaf(a.x, b.x, fmaf(a.y, b.y, fmaf(a.z, b.z, a.w * b.w)));
}

// One routing pass. W streamed once per batch-half: block = (j-chunk, batch-half),
// all n on lanes (softmax = 6 shfl_xor). Granule = [64n][8d: d==q mod 4][16i] = 32KB,
// 64B-line-dense global reads, 4 LDS buffers, prefetch-2, counted vmcnt(4).
// LDS slot XOR-swizzled s = l^(n&31) (source-side pre-swizzle, linear dest; read with
// same XOR — rule 21). vs (routing weights) NOT register-resident: re-read from L2 in
// finishJ with a vmcnt(0) drain (W granules in flight have long landed by then).
template <int MODE>
__global__ __launch_bounds__(THREADS, 2)
void caps_pass(const float* __restrict__ xg, const float* __restrict__ Wg,
               const float* __restrict__ vsumg, float* __restrict__ s)
{
    __shared__ float qb0[NN * DD * II / 4];  // 32KB granule buffers
    __shared__ float qb1[NN * DD * II / 4];
    __shared__ float qb2[NN * DD * II / 4];
    __shared__ float qb3[NN * DD * II / 4];
    __shared__ float xs[BSUB * JC * II];     // 16KB
    __shared__ float lpb[2][BSUB][NN];       // 8KB partial logits per d-half

    const int t    = threadIdx.x;
    const int n    = t & 63;             // capsule (lane)
    const int w    = t >> 6;             // wave 0..7
    const int bq   = w >> 1;             // b-quad 0..3
    const int dh   = w & 1;              // d-half 0..1

    // XCD pairing: both batch-halves of a j-chunk land on the same XCD (id%8 = jc%8)
    const int id = blockIdx.x;
    const int jc = (id & 7) + ((id >> 4) << 3);   // 0..127
    const int bh = (id >> 3) & 1;
    const int j0 = jc * JC;
    const int b0 = bh * BSUB;

    // stage x tile (16KB), dest linear in thread id
    #pragma unroll
    for (int it = 0; it < 2; ++it) {
        const int T = t + it * THREADS;       // 0..1023
        const int p = T >> 2, quad = T & 3;   // p = bl*16+jj
        const int bl = p >> 4, jj = p & 15;
        const float* src = xg + ((size_t)(b0 + bl) * JJ + (j0 + jj)) * II + quad * 4;
        gload_lds16(src, xs + (size_t)T * 4);
    }

    // granule G = jj*4 + dq covers d == dq (mod 4), all 16 i, all 64 n.
    // LDS float4-slot s of row n holds logical l = s^(n&31), l = dr*4+iq, d = dq+dr*4.
    auto issueG = [&](int Gi, float* buf) {
        const int G  = Gi > 63 ? 63 : Gi;     // tail clamp keeps vmcnt counts uniform
        const int jg = G >> 2, dq = G & 3;
        #pragma unroll
        for (int it = 0; it < 4; ++it) {
            const int T  = t + it * THREADS;  // 0..2047
            const int nr = T >> 5;            // row 0..63
            const int sl = T & 31;            // dest float4-slot
            const int l  = sl ^ (nr & 31);
            const int dr = l >> 2, iq = l & 3;
            const float* src = Wg + ((size_t)nr * JJ + (j0 + jg)) * (DD * II)
                                  + (dq + dr * 4) * II + iq * 4;
            gload_lds16(src, buf + (size_t)T * 4);
        }
    };

    float uh[4][16];    // u_hat (MODE1 only; elided in MODE0)
    float sacc[4][16];  // s accumulator
    #pragma unroll
    for (int bb = 0; bb < 4; ++bb)
        #pragma unroll
        for (int dd = 0; dd < 16; ++dd) { sacc[bb][dd] = 0.f; if (MODE) uh[bb][dd] = 0.f; }

    // compute granule (jj, q): thread handles its 4 d-rows (dd = q + dr'*4) x 4 b.
    // iq-outer keeps transients at xqb(16) + w4(4) regs; W and x each read once.
    auto computeG = [&](int jj, int q, const float* buf) {
        const float4* bv = (const float4*)buf;
        const float4* xv = (const float4*)xs;
        #pragma unroll
        for (int iq = 0; iq < 4; ++iq) {
            float4 xqb[4];
            #pragma unroll
            for (int bb = 0; bb < 4; ++bb)   // wave-uniform addr -> LDS broadcast
                xqb[bb] = xv[((bq * 4 + bb) * JC + jj) * 4 + iq];
            #pragma unroll
            for (int drp = 0; drp < 4; ++drp) {
                const int l  = (dh * 4 + drp) * 4 + iq;
                const int sl = l ^ (n & 31);
                const float4 w4 = bv[n * 32 + sl];
                const int dd = q + drp * 4;   // static: q, drp compile-time
                #pragma unroll
                for (int bb = 0; bb < 4; ++bb) {
                    float& acc = MODE ? uh[bb][dd] : sacc[bb][dd];
                    acc += dot4(w4, xqb[bb]);
                }
            }
        }
    };

    // 4-buffer pipeline, prefetch depth 2, counted vmcnt(4) (never drained in-loop
    // except the per-j vs-read drain in finishJ, by which time granules have landed).
    float* bufs[4] = { qb0, qb1, qb2, qb3 };
    issueG(0, bufs[0]);
    issueG(1, bufs[1]);

    for (int jj = 0; jj < JC; ++jj) {
        #pragma unroll
        for (int q = 0; q < 4; ++q) {
            asm volatile("s_waitcnt vmcnt(4)" ::: "memory");  // granule (jj,q) landed
            __builtin_amdgcn_s_barrier();
            asm volatile("" ::: "memory");
            issueG(jj * 4 + q + 2, bufs[(q + 2) & 3]);        // static buffer idx
            computeG(jj, q, bufs[q]);
        }
        if (MODE) {
            // logits: lp[bb] = <uh[bb], vsum[b,n,:]>, vs streamed from L2 in bb-pairs
            float lp[4];
            #pragma unroll
            for (int bp = 0; bp < 2; ++bp) {
                float4 vsl[2][4];
                #pragma unroll
                for (int u = 0; u < 2; ++u) {
                    const int bb = bp * 2 + u;
                    const float4* vp = (const float4*)(vsumg
                        + ((size_t)(b0 + bq * 4 + bb) * NN + n) * DD + dh * 16);
                    #pragma unroll
                    for (int q4 = 0; q4 < 4; ++q4) vsl[u][q4] = vp[q4];
                }
                asm volatile("s_waitcnt vmcnt(0)" ::: "memory");
                #pragma unroll
                for (int u = 0; u < 2; ++u) {
                    const int bb = bp * 2 + u;
                    float acc = 0.f;
                    #pragma unroll
                    for (int q4 = 0; q4 < 4; ++q4) {
                        acc = fmaf(uh[bb][q4 * 4 + 0], vsl[u][q4].x, acc);
                        acc = fmaf(uh[bb][q4 * 4 + 1], vsl[u][q4].y, acc);
                        acc = fmaf(uh[bb][q4 * 4 + 2], vsl[u][q4].z, acc);
                        acc = fmaf(uh[bb][q4 * 4 + 3], vsl[u][q4].w, acc);
                    }
                    lp[bb] = acc;
                }
            }
            #pragma unroll
            for (int bb = 0; bb < 4; ++bb) lpb[dh][bq * 4 + bb][n] = lp[bb];
            asm volatile("s_waitcnt lgkmcnt(0)" ::: "memory");
            __builtin_amdgcn_s_barrier();
            asm volatile("" ::: "memory");
            #pragma unroll
            for (int bb = 0; bb < 4; ++bb) {
                lp[bb] += lpb[1 - dh][bq * 4 + bb][n];
                float m = lp[bb];
                #pragma unroll
                for (int off = 1; off < 64; off <<= 1) m = fmaxf(m, __shfl_xor(m, off));
                const float e = __expf(lp[bb] - m);
                float es = e;
                #pragma unroll
                for (int off = 1; off < 64; off <<= 1) es += __shfl_xor(es, off);
                const float c = e / es;
                #pragma unroll
                for (int dd = 0; dd < 16; ++dd) {
                    sacc[bb][dd] = fmaf(c, uh[bb][dd], sacc[bb][dd]);
                    uh[bb][dd] = 0.f;
                }
            }
        }
    }

    const float cs = MODE ? 1.0f : (1.0f / 64.0f);
    #pragma unroll
    for (int bb = 0; bb < 4; ++bb) {
        float* sp = s + ((size_t)(b0 + bq * 4 + bb) * NN + n) * DD + dh * 16;
        #pragma unroll
        for (int dd = 0; dd < 16; ++dd)
            atomicAdd(sp + dd, sacc[bb][dd] * cs);
    }
}

// v = squash(s); out = v; vsum += v (linearized-logit trick: pass r uses <v0+..+v_{r-1}, u>)
__global__ __launch_bounds__(256)
void caps_squash(const float* __restrict__ s, float* __restrict__ vsum,
                 float* __restrict__ out) {
    const int idx = blockIdx.x * 256 + threadIdx.x;   // 0 .. B*N*D-1
    const float sv = s[idx];
    float sq = sv * sv;
    sq += __shfl_xor(sq, 1);
    sq += __shfl_xor(sq, 2);
    sq += __shfl_xor(sq, 4);
    sq += __shfl_xor(sq, 8);
    sq += __shfl_xor(sq, 16);
    const float s2 = sq;
    const float scale = s2 / (1.0f + s2) / sqrtf(s2 + 1e-7f);
    const float v = scale * sv;
    out[idx] = v;
    vsum[idx] += v;
}

extern "C" void kernel_launch(void* const* d_in, const int* in_sizes, int n_in,
                              void* d_out, int out_size, void* d_ws, size_t ws_size,
                              hipStream_t stream) {
    const float* x = (const float*)d_in[0];   // [32,2048,16]
    const float* W = (const float*)d_in[1];   // [64,2048,32,16]
    float* out = (float*)d_out;               // [32,64,32]

    float* s    = (float*)d_ws;               // B*N*D floats
    float* vsum = s + BBATCH * NN * DD;       // B*N*D floats

    const size_t sbytes = (size_t)BBATCH * NN * DD * sizeof(float);
    const int sqblocks = (BBATCH * NN * DD) / 256;

    hipMemsetAsync(s, 0, 2 * sbytes, stream);

    // r = 0: c uniform (1/64)
    caps_pass<0><<<256, THREADS, 0, stream>>>(x, W, vsum, s);
    caps_squash<<<sqblocks, 256, 0, stream>>>(s, vsum, out);   // v0; vsum = v0

    // r = 1: logits = <v0, u_hat>
    hipMemsetAsync(s, 0, sbytes, stream);
    caps_pass<1><<<256, THREADS, 0, stream>>>(x, W, vsum, s);
    caps_squash<<<sqblocks, 256, 0, stream>>>(s, vsum, out);   // v1; vsum = v0+v1

    // r = 2: logits = <v0+v1, u_hat>
    hipMemsetAsync(s, 0, sbytes, stream);
    caps_pass<1><<<256, THREADS, 0, stream>>>(x, W, vsum, s);
    caps_squash<<<sqblocks, 256, 0, stream>>>(s, vsum, out);   // v2 -> d_out
}